// Round 1
// 880.487 us; speedup vs baseline: 1.5525x; 1.5525x over previous
//
#include <hip/hip_runtime.h>

// ---------- types ----------
typedef short v8s __attribute__((ext_vector_type(8)));
typedef float v4f __attribute__((ext_vector_type(4)));
typedef unsigned long long u64;

union U2 {
    u64 u[2];
    v8s v;
};

static __device__ __forceinline__ unsigned short f2bf(float x) {
    unsigned u = __builtin_bit_cast(unsigned, x);
    unsigned r = (u + 0x7fffu + ((u >> 16) & 1u)) >> 16;
    return (unsigned short)r;
}

static __device__ __forceinline__ float sigm(float x) {
    return 1.f / (1.f + __expf(-x));
}
static __device__ __forceinline__ float tanh_fast(float x) {
    x = fminf(fmaxf(x, -15.f), 15.f);
    float e = __expf(2.f * x);
    return (e - 1.f) / (e + 1.f);
}

// ---------- elementwise f32 -> bf16 convert ----------
__global__ void cvt_bf16(const float* __restrict__ src, unsigned short* __restrict__ dst, int n) {
    int i = blockIdx.x * 256 + threadIdx.x;
    if (i < n) dst[i] = f2bf(src[i]);
}

// ---------- repack W_hh (f32 [1536][512]) into MFMA B-fragment order ----------
// dst: [96 tiles][16 kf][64 lane][8 i] bf16, per dir.
__global__ void repack_whh(const float* __restrict__ src, unsigned short* __restrict__ dst) {
    long e = (long)blockIdx.x * 256 + threadIdx.x;  // < 786432
    int i = e & 7;
    int lane = (e >> 3) & 63;
    int kf = (e >> 9) & 15;
    int T = (int)(e >> 13);  // 0..95
    int gcol = T * 16 + (lane & 15);
    int k = kf * 32 + (lane >> 4) * 8 + i;
    dst[e] = f2bf(src[(long)gcol * 512 + k]);
}

// ---------- zero team flags (every launch, incl. graph replays) ----------
// 16 teams x 64 per-wave flags = 1024 dwords
__global__ void init_flags(unsigned int* __restrict__ p) {
    p[blockIdx.x * 256 + threadIdx.x] = 0;
}

// ---------- build X = concat(embed_table[slot_ids], value_embeds) as bf16 [16384][1024] ----------
__global__ void build_x(const int* __restrict__ slot_ids,
                        const float* __restrict__ value_embeds,
                        const float* __restrict__ embed_table,
                        unsigned short* __restrict__ X) {
    int r = blockIdx.x;           // r = b*64 + s
    int t = threadIdx.x;          // 256 threads
    int id = slot_ids[r];
    X[(long)r * 1024 + t] = f2bf(embed_table[id * 256 + t]);
#pragma unroll
    for (int i = 0; i < 3; i++) {
        int c = t + i * 256;
        X[(long)r * 1024 + 256 + c] = f2bf(value_embeds[(long)r * 768 + c]);
    }
}

// ---------- bf16 MFMA GEMM: C[M][N] = A[M][K] * Bt[N][K]^T ----------
// EPI=0: plain f32 store C[row*N+col]
// EPI=1: scatter gi packed for gru_rec consumers:
//   [d][s][bg 8][cb 16][wave 4][g 3][lane 64][r 4] f32
template <int EPI>
__global__ __launch_bounds__(256) void gemm_bt(const unsigned short* __restrict__ A,
                                               const unsigned short* __restrict__ Bt,
                                               float* __restrict__ C,
                                               int M, int N, int K) {
    const int LDT = 72;
    __shared__ unsigned short As[128 * 72];
    __shared__ unsigned short Bs[128 * 72];
    int tid = threadIdx.x;
    int lane = tid & 63;
    int wave = tid >> 6;
    int gm0 = blockIdx.y * 128;
    int gn0 = blockIdx.x * 128;
    int wm0 = (wave >> 1) * 64;
    int wn0 = (wave & 1) * 64;
    int q = lane >> 4;
    int l16 = lane & 15;

    v4f acc[4][4];
#pragma unroll
    for (int i = 0; i < 4; i++)
#pragma unroll
        for (int j = 0; j < 4; j++) acc[i][j] = v4f{0.f, 0.f, 0.f, 0.f};

    for (int k0 = 0; k0 < K; k0 += 64) {
#pragma unroll
        for (int l = tid; l < 1024; l += 256) {
            int row = l >> 3;
            int col = (l & 7) * 8;
            *(v8s*)&As[row * LDT + col] = *(const v8s*)&A[(long)(gm0 + row) * K + k0 + col];
            *(v8s*)&Bs[row * LDT + col] = *(const v8s*)&Bt[(long)(gn0 + row) * K + k0 + col];
        }
        __syncthreads();
#pragma unroll
        for (int kf = 0; kf < 2; kf++) {
            v8s af[4], bfr[4];
#pragma unroll
            for (int mi = 0; mi < 4; mi++)
                af[mi] = *(const v8s*)&As[(wm0 + mi * 16 + l16) * LDT + kf * 32 + q * 8];
#pragma unroll
            for (int ni = 0; ni < 4; ni++)
                bfr[ni] = *(const v8s*)&Bs[(wn0 + ni * 16 + l16) * LDT + kf * 32 + q * 8];
#pragma unroll
            for (int mi = 0; mi < 4; mi++)
#pragma unroll
                for (int ni = 0; ni < 4; ni++)
                    acc[mi][ni] = __builtin_amdgcn_mfma_f32_16x16x32_bf16(af[mi], bfr[ni], acc[mi][ni], 0, 0, 0);
        }
        __syncthreads();
    }

#pragma unroll
    for (int mi = 0; mi < 4; mi++)
#pragma unroll
        for (int ni = 0; ni < 4; ni++) {
            int col = gn0 + wn0 + ni * 16 + l16;
#pragma unroll
            for (int r = 0; r < 4; r++) {
                int row = gm0 + wm0 + mi * 16 + q * 4 + r;
                float v = acc[mi][ni][r];
                if (EPI == 0) {
                    C[(long)row * N + col] = v;
                } else {
                    int dd = (col >= 1536) ? 1 : 0;
                    int gcol = col - dd * 1536;
                    int g = gcol >> 9;
                    int jj = gcol & 511;
                    int cb = jj >> 5;
                    int jc = jj & 31;
                    int jhc = jc >> 4;
                    int l16c = jc & 15;
                    int b = row >> 6, s = row & 63;
                    int bg = b >> 5, brow = b & 31;
                    int rgc = brow >> 4, m = brow & 15;
                    int qc = m >> 2, rc = m & 3;
                    int wv = rgc * 2 + jhc;
                    long idx = (((((long)(dd * 64 + s) * 8 + bg) * 16 + cb) * 4 + wv) * 3 + g) * 256 +
                               (qc * 16 + l16c) * 4 + rc;
                    C[idx] = v;
                }
            }
        }
}

// ---------- GRU recurrence: all-register, per-wave flags, no LDS, no barriers ----------
// 256 blocks x 256 threads (1 block/CU forced by ~330 VGPRs). blk = d*128 + bg*16 + cb.
// team = (d,bg): 16 blocks x 4 waves = 64 producer waves splitting 512 h-cols.
// Per wave, held in registers for the whole kernel:
//   - its W_hh B-fragments: 48 x v8s = 192 VGPRs (step-invariant, loaded once)
//   - gi for the CURRENT step (prefetched one step ahead, full-step latency cover)
// Per step (per wave, autonomous — no __syncthreads anywhere in the loop):
//   poll 64 team flags >= t (one coalesced load / iter) ->
//   32 x 8B relaxed-agent loads: h_{t-1} A-fragments straight from LLC exchange buf ->
//   48 reg-only MFMA -> gate epilogue -> 4 packed sc1 dword stores ->
//   s_waitcnt vmcnt(0) -> per-wave flag store (RELAXED, not RELEASE: sc1 stores are
//   LLC-visible at vmcnt retirement; release's buffer_wbl2 only ordered the plain hout
//   stores, which nothing reads during this kernel) ->
//   off-path: hout stores + next-step gi prefetch (in flight across the next poll).
// Parity double-buffer, max skew 1 step; WAR safe because a wave's buf reads retire
// before its own vmcnt(0)+flag, which gates any peer's next-parity writes.
__global__ __launch_bounds__(256, 1) void gru_rec(const float* __restrict__ gi,           // packed, see EPI=1
                                                  const unsigned short* __restrict__ Wpk, // [2][96][16][64][8]
                                                  const float* __restrict__ bih_f,
                                                  const float* __restrict__ bhh_f,
                                                  const float* __restrict__ bih_b,
                                                  const float* __restrict__ bhh_b,
                                                  unsigned short* __restrict__ hout,      // [256][64][1024]
                                                  unsigned int* __restrict__ hshd,        // [16][2][8192] dwords
                                                  unsigned int* __restrict__ flags) {     // [16][64]
    int tid = threadIdx.x;
    int lane = tid & 63;
    int wave = tid >> 6;          // 0..3
    int q = lane >> 4, l16 = lane & 15;
    int blk = blockIdx.x;
    int d = blk >> 7;
    int bg = (blk >> 4) & 7;
    int cb = blk & 15;
    int team = d * 8 + bg;
    int rg = wave >> 1, jh = wave & 1;
    int j = cb * 32 + jh * 16 + l16;   // owned h-col

    // W_hh B-fragments into registers (step-invariant): 3 gates x 16 kf x v8s
    v8s bfr[3][16];
#pragma unroll
    for (int g = 0; g < 3; g++) {
        const unsigned short* wp = Wpk + ((long)d * 96 + (g * 32 + cb * 2 + jh)) * 8192;
#pragma unroll
        for (int kf = 0; kf < 16; kf++)
            bfr[g][kf] = *(const v8s*)&wp[(kf * 64 + lane) * 8];
    }

    float bi[3], bh[3];
    {
        const float* bihp = d ? bih_b : bih_f;
        const float* bhhp = d ? bhh_b : bhh_f;
#pragma unroll
        for (int g = 0; g < 3; g++) {
            bi[g] = bihp[g * 512 + j];
            bh[g] = bhhp[g * 512 + j];
        }
    }
    float hreg[4] = {0.f, 0.f, 0.f, 0.f};

    unsigned int* myflags = flags + team * 64;
    unsigned int* hsteam = hshd + (long)team * 2 * 8192;

    // prefetch gi for t = 0
    v4f gir[3];
    {
        int s0 = d ? 63 : 0;
        const float* gp = gi + (((((long)(d * 64 + s0)) * 8 + bg) * 16 + cb) * 4 + wave) * 768 + lane * 4;
#pragma unroll
        for (int g = 0; g < 3; g++) gir[g] = __builtin_nontemporal_load((const v4f*)(gp + g * 256));
    }

    for (int t = 0; t < 64; t++) {
        int s = d ? (63 - t) : t;

        v4f acc[3];
#pragma unroll
        for (int g = 0; g < 3; g++) acc[g] = v4f{0.f, 0.f, 0.f, 0.f};

        if (t > 0) {
            // per-wave poll: all 64 producer-wave flags of this team must reach t
            while (__hip_atomic_load(&myflags[lane], __ATOMIC_RELAXED, __HIP_MEMORY_SCOPE_AGENT) <
                   (unsigned)t)
                __builtin_amdgcn_s_sleep(1);

            // h_{t-1} A-fragments straight from the exchange buffer (row-major [32][512] bf16)
            const char* hb = (const char*)hsteam + ((t + 1) & 1) * 32768 +
                             (rg * 16 + l16) * 1024 + q * 16;
            v8s af[16];
#pragma unroll
            for (int kf = 0; kf < 16; kf++) {
                u64 lo = __hip_atomic_load((const u64*)(hb + kf * 64), __ATOMIC_RELAXED,
                                           __HIP_MEMORY_SCOPE_AGENT);
                u64 hi = __hip_atomic_load((const u64*)(hb + kf * 64 + 8), __ATOMIC_RELAXED,
                                           __HIP_MEMORY_SCOPE_AGENT);
                U2 u;
                u.u[0] = lo;
                u.u[1] = hi;
                af[kf] = u.v;
            }
#pragma unroll
            for (int kf = 0; kf < 16; kf++)
#pragma unroll
                for (int g = 0; g < 3; g++)
                    acc[g] = __builtin_amdgcn_mfma_f32_16x16x32_bf16(af[kf], bfr[g][kf], acc[g], 0, 0, 0);
        }

        // combine gates, update h, publish exchange slice (sc1 dword stores)
        unsigned int* dst = hsteam + (t & 1) * 8192;
        unsigned short hv[4];
#pragma unroll
        for (int r = 0; r < 4; r++) {
            float rr = sigm(gir[0][r] + bi[0] + acc[0][r] + bh[0]);
            float zz = sigm(gir[1][r] + bi[1] + acc[1][r] + bh[1]);
            float nn = tanh_fast(gir[2][r] + bi[2] + rr * (acc[2][r] + bh[2]));
            float hn = (1.f - zz) * nn + zz * hreg[r];
            hreg[r] = hn;
            hv[r] = f2bf(hn);
            float pv = __shfl_xor(hn, 1);
            if ((l16 & 1) == 0) {
                unsigned int pack = (unsigned int)hv[r] | ((unsigned int)f2bf(pv) << 16);
                int row = rg * 16 + q * 4 + r;
                __hip_atomic_store(&dst[row * 256 + (j >> 1)], pack, __ATOMIC_RELAXED,
                                   __HIP_MEMORY_SCOPE_AGENT);
            }
        }

        // drain this wave's sc1 stores to the coherence point, then publish per-wave flag
        asm volatile("s_waitcnt vmcnt(0)" ::: "memory");
        if (lane == 0)
            __hip_atomic_store(&myflags[cb * 4 + wave], (unsigned)(t + 1), __ATOMIC_RELAXED,
                               __HIP_MEMORY_SCOPE_AGENT);

        // off the critical path: final output + next-step gi prefetch
#pragma unroll
        for (int r = 0; r < 4; r++) {
            int row = rg * 16 + q * 4 + r;
            hout[((long)(bg * 32 + row) * 64 + s) * 1024 + d * 512 + j] = hv[r];
        }
        if (t < 63) {
            int sn = d ? (62 - t) : (t + 1);
            const float* gp =
                gi + (((((long)(d * 64 + sn)) * 8 + bg) * 16 + cb) * 4 + wave) * 768 + lane * 4;
#pragma unroll
            for (int g = 0; g < 3; g++) gir[g] = __builtin_nontemporal_load((const v4f*)(gp + g * 256));
        }
    }
}

extern "C" void kernel_launch(void* const* d_in, const int* in_sizes, int n_in,
                              void* d_out, int out_size, void* d_ws, size_t ws_size,
                              hipStream_t stream) {
    const int* slot_ids = (const int*)d_in[0];
    const float* value_embeds = (const float*)d_in[1];
    const float* embed_table = (const float*)d_in[2];
    const float* W_ih_f = (const float*)d_in[3];
    const float* W_hh_f = (const float*)d_in[4];
    const float* b_ih_f = (const float*)d_in[5];
    const float* b_hh_f = (const float*)d_in[6];
    const float* W_ih_b = (const float*)d_in[7];
    const float* W_hh_b = (const float*)d_in[8];
    const float* b_ih_b = (const float*)d_in[9];
    const float* b_hh_b = (const float*)d_in[10];
    const float* W_proj = (const float*)d_in[11];
    float* out = (float*)d_out;
    char* ws = (char*)d_ws;

    // workspace layout (bytes)
    unsigned short* X = (unsigned short*)(ws + 0);              // 16384x1024 bf16 = 33,554,432
    float* gi = (float*)(ws + 33554432);                        // 50,331,648 f32 = 201,326,592
    unsigned short* Wstk = (unsigned short*)(ws + 234881024);   // 3072x1024 bf16 = 6,291,456 (dead after gemm1)
    unsigned short* Wpk = (unsigned short*)(ws + 241172480);    // 2x96x16x64x8 bf16 = 3,145,728
    unsigned short* Wp = (unsigned short*)(ws + 244318208);     // 512x1024 bf16 = 1,048,576
    unsigned short* hout = X;  // alias: X dead after gemm1
    // h-share + flags alias the (dead-after-gemm1) Wstk region
    unsigned int* hshd = (unsigned int*)Wstk;                   // 16*2*8192 dwords = 1 MB
    unsigned int* flags = (unsigned int*)(ws + 234881024 + 1048576);  // 1024 dwords

    cvt_bf16<<<6144, 256, 0, stream>>>(W_ih_f, Wstk, 1536 * 1024);
    cvt_bf16<<<6144, 256, 0, stream>>>(W_ih_b, Wstk + 1536 * 1024, 1536 * 1024);
    repack_whh<<<3072, 256, 0, stream>>>(W_hh_f, Wpk);
    repack_whh<<<3072, 256, 0, stream>>>(W_hh_b, Wpk + 786432);
    cvt_bf16<<<2048, 256, 0, stream>>>(W_proj, Wp, 512 * 1024);
    build_x<<<16384, 256, 0, stream>>>(slot_ids, value_embeds, embed_table, X);

    // gi = X @ [Wih_f; Wih_b]^T  (M=16384, N=3072, K=1024), packed epilogue
    gemm_bt<1><<<dim3(24, 128), 256, 0, stream>>>(X, Wstk, gi, 16384, 3072, 1024);

    // zero flags (after gemm1: aliases Wstk region)
    init_flags<<<4, 256, 0, stream>>>(flags);

    // recurrence: 256 co-resident blocks, all-register, per-wave flag sync
    gru_rec<<<256, 256, 0, stream>>>(gi, Wpk, b_ih_f, b_hh_f, b_ih_b, b_hh_b, hout, hshd, flags);

    // out = hcat @ W_proj^T   (M=16384, N=512, K=1024)
    gemm_bt<0><<<dim3(4, 128), 256, 0, stream>>>(hout, Wp, out, 16384, 512, 1024);
}

// Round 3
// 841.806 us; speedup vs baseline: 1.6239x; 1.0460x over previous
//
#include <hip/hip_runtime.h>

// ---------- types ----------
typedef short v8s __attribute__((ext_vector_type(8)));
typedef float v4f __attribute__((ext_vector_type(4)));
typedef unsigned int v4u __attribute__((ext_vector_type(4)));
typedef unsigned long long u64;

static __device__ __forceinline__ unsigned short f2bf(float x) {
    unsigned u = __builtin_bit_cast(unsigned, x);
    unsigned r = (u + 0x7fffu + ((u >> 16) & 1u)) >> 16;
    return (unsigned short)r;
}

static __device__ __forceinline__ float sigm(float x) {
    return 1.f / (1.f + __expf(-x));
}
static __device__ __forceinline__ float tanh_fast(float x) {
    x = fminf(fmaxf(x, -15.f), 15.f);
    float e = __expf(2.f * x);
    return (e - 1.f) / (e + 1.f);
}

// ---------- elementwise f32 -> bf16 convert ----------
__global__ void cvt_bf16(const float* __restrict__ src, unsigned short* __restrict__ dst, int n) {
    int i = blockIdx.x * 256 + threadIdx.x;
    if (i < n) dst[i] = f2bf(src[i]);
}

// ---------- repack W_hh (f32 [1536][512]) into MFMA B-fragment order ----------
// dst: [96 tiles][16 kf][64 lane][8 i] bf16, per dir.
__global__ void repack_whh(const float* __restrict__ src, unsigned short* __restrict__ dst) {
    long e = (long)blockIdx.x * 256 + threadIdx.x;  // < 786432
    int i = e & 7;
    int lane = (e >> 3) & 63;
    int kf = (e >> 9) & 15;
    int T = (int)(e >> 13);  // 0..95
    int gcol = T * 16 + (lane & 15);
    int k = kf * 32 + (lane >> 4) * 8 + i;
    dst[e] = f2bf(src[(long)gcol * 512 + k]);
}

// ---------- zero team flags (every launch, incl. graph replays) ----------
// 16 teams x 64 per-wave flags = 1024 dwords
__global__ void init_flags(unsigned int* __restrict__ p) {
    p[blockIdx.x * 256 + threadIdx.x] = 0;
}

// ---------- build X = concat(embed_table[slot_ids], value_embeds) as bf16 [16384][1024] ----------
__global__ void build_x(const int* __restrict__ slot_ids,
                        const float* __restrict__ value_embeds,
                        const float* __restrict__ embed_table,
                        unsigned short* __restrict__ X) {
    int r = blockIdx.x;           // r = b*64 + s
    int t = threadIdx.x;          // 256 threads
    int id = slot_ids[r];
    X[(long)r * 1024 + t] = f2bf(embed_table[id * 256 + t]);
#pragma unroll
    for (int i = 0; i < 3; i++) {
        int c = t + i * 256;
        X[(long)r * 1024 + 256 + c] = f2bf(value_embeds[(long)r * 768 + c]);
    }
}

// ---------- bf16 MFMA GEMM: C[M][N] = A[M][K] * Bt[N][K]^T ----------
// EPI=0: plain f32 store C[row*N+col]
// EPI=1: scatter gi packed for gru_rec consumers:
//   [d][s][bg 8][cb 16][wave 4][g 3][lane 64][r 4] f32
template <int EPI>
__global__ __launch_bounds__(256) void gemm_bt(const unsigned short* __restrict__ A,
                                               const unsigned short* __restrict__ Bt,
                                               float* __restrict__ C,
                                               int M, int N, int K) {
    const int LDT = 72;
    __shared__ unsigned short As[128 * 72];
    __shared__ unsigned short Bs[128 * 72];
    int tid = threadIdx.x;
    int lane = tid & 63;
    int wave = tid >> 6;
    int gm0 = blockIdx.y * 128;
    int gn0 = blockIdx.x * 128;
    int wm0 = (wave >> 1) * 64;
    int wn0 = (wave & 1) * 64;
    int q = lane >> 4;
    int l16 = lane & 15;

    v4f acc[4][4];
#pragma unroll
    for (int i = 0; i < 4; i++)
#pragma unroll
        for (int j = 0; j < 4; j++) acc[i][j] = v4f{0.f, 0.f, 0.f, 0.f};

    for (int k0 = 0; k0 < K; k0 += 64) {
#pragma unroll
        for (int l = tid; l < 1024; l += 256) {
            int row = l >> 3;
            int col = (l & 7) * 8;
            *(v8s*)&As[row * LDT + col] = *(const v8s*)&A[(long)(gm0 + row) * K + k0 + col];
            *(v8s*)&Bs[row * LDT + col] = *(const v8s*)&Bt[(long)(gn0 + row) * K + k0 + col];
        }
        __syncthreads();
#pragma unroll
        for (int kf = 0; kf < 2; kf++) {
            v8s af[4], bfr[4];
#pragma unroll
            for (int mi = 0; mi < 4; mi++)
                af[mi] = *(const v8s*)&As[(wm0 + mi * 16 + l16) * LDT + kf * 32 + q * 8];
#pragma unroll
            for (int ni = 0; ni < 4; ni++)
                bfr[ni] = *(const v8s*)&Bs[(wn0 + ni * 16 + l16) * LDT + kf * 32 + q * 8];
#pragma unroll
            for (int mi = 0; mi < 4; mi++)
#pragma unroll
                for (int ni = 0; ni < 4; ni++)
                    acc[mi][ni] = __builtin_amdgcn_mfma_f32_16x16x32_bf16(af[mi], bfr[ni], acc[mi][ni], 0, 0, 0);
        }
        __syncthreads();
    }

#pragma unroll
    for (int mi = 0; mi < 4; mi++)
#pragma unroll
        for (int ni = 0; ni < 4; ni++) {
            int col = gn0 + wn0 + ni * 16 + l16;
#pragma unroll
            for (int r = 0; r < 4; r++) {
                int row = gm0 + wm0 + mi * 16 + q * 4 + r;
                float v = acc[mi][ni][r];
                if (EPI == 0) {
                    C[(long)row * N + col] = v;
                } else {
                    int dd = (col >= 1536) ? 1 : 0;
                    int gcol = col - dd * 1536;
                    int g = gcol >> 9;
                    int jj = gcol & 511;
                    int cb = jj >> 5;
                    int jc = jj & 31;
                    int jhc = jc >> 4;
                    int l16c = jc & 15;
                    int b = row >> 6, s = row & 63;
                    int bg = b >> 5, brow = b & 31;
                    int rgc = brow >> 4, m = brow & 15;
                    int qc = m >> 2, rc = m & 3;
                    int wv = rgc * 2 + jhc;
                    long idx = (((((long)(dd * 64 + s) * 8 + bg) * 16 + cb) * 4 + wv) * 3 + g) * 256 +
                               (qc * 16 + l16c) * 4 + rc;
                    C[idx] = v;
                }
            }
        }
}

// ---------- GRU recurrence: all-register, per-wave flags, no LDS, no barriers ----------
// 256 blocks x 256 threads (1 block/CU). blk = d*128 + bg*16 + cb.
// team = (d,bg): 16 blocks x 4 waves = 64 producer waves splitting 512 h-cols.
// Per step (per wave, autonomous):
//   poll 64 team flags >= t ->
//   16 x global_load_dwordx4 sc1 (inline asm, ALL IN FLIGHT: one LLC round trip,
//     not 32 serial atomic-load round trips). Outputs are EARLY-CLOBBER ("=&v"):
//     global_load writes dst asynchronously, so without & the allocator may overlap
//     dst with the address pair -> first data return clobbers the base while later
//     loads issue -> memory fault (that was round 2's crash). ->
//   single s_waitcnt vmcnt(0) + sched_barrier ->
//   48 reg-only MFMA -> gate epilogue -> 4 packed sc1 dword stores ->
//   s_waitcnt vmcnt(0) -> per-wave flag store (relaxed: sc1 stores are LLC-visible
//   at vmcnt retirement) -> off-path: hout stores + next-step gi prefetch.
// Parity double-buffer, max skew 1 step; WAR safe: a wave's buf reads retire before
// its own vmcnt(0)+flag, which gates any peer's next-parity writes.
__global__ __launch_bounds__(256, 1) void gru_rec(const float* __restrict__ gi,           // packed, see EPI=1
                                                  const unsigned short* __restrict__ Wpk, // [2][96][16][64][8]
                                                  const float* __restrict__ bih_f,
                                                  const float* __restrict__ bhh_f,
                                                  const float* __restrict__ bih_b,
                                                  const float* __restrict__ bhh_b,
                                                  unsigned short* __restrict__ hout,      // [256][64][1024]
                                                  unsigned int* __restrict__ hshd,        // [16][2][8192] dwords
                                                  unsigned int* __restrict__ flags) {     // [16][64]
    int tid = threadIdx.x;
    int lane = tid & 63;
    int wave = tid >> 6;          // 0..3
    int q = lane >> 4, l16 = lane & 15;
    int blk = blockIdx.x;
    int d = blk >> 7;
    int bg = (blk >> 4) & 7;
    int cb = blk & 15;
    int team = d * 8 + bg;
    int rg = wave >> 1, jh = wave & 1;
    int j = cb * 32 + jh * 16 + l16;   // owned h-col

    // W_hh B-fragments (step-invariant): 3 gates x 16 kf x v8s
    v8s bfr[3][16];
#pragma unroll
    for (int g = 0; g < 3; g++) {
        const unsigned short* wp = Wpk + ((long)d * 96 + (g * 32 + cb * 2 + jh)) * 8192;
#pragma unroll
        for (int kf = 0; kf < 16; kf++)
            bfr[g][kf] = *(const v8s*)&wp[(kf * 64 + lane) * 8];
    }

    float bi[3], bh[3];
    {
        const float* bihp = d ? bih_b : bih_f;
        const float* bhhp = d ? bhh_b : bhh_f;
#pragma unroll
        for (int g = 0; g < 3; g++) {
            bi[g] = bihp[g * 512 + j];
            bh[g] = bhhp[g * 512 + j];
        }
    }
    float hreg[4] = {0.f, 0.f, 0.f, 0.f};

    unsigned int* myflags = flags + team * 64;
    unsigned int* hsteam = hshd + (long)team * 2 * 8192;

    // prefetch gi for t = 0
    v4f gir[3];
    {
        int s0 = d ? 63 : 0;
        const float* gp = gi + (((((long)(d * 64 + s0)) * 8 + bg) * 16 + cb) * 4 + wave) * 768 + lane * 4;
#pragma unroll
        for (int g = 0; g < 3; g++) gir[g] = __builtin_nontemporal_load((const v4f*)(gp + g * 256));
    }

    for (int t = 0; t < 64; t++) {
        int s = d ? (63 - t) : t;

        v4f acc[3];
#pragma unroll
        for (int g = 0; g < 3; g++) acc[g] = v4f{0.f, 0.f, 0.f, 0.f};

        if (t > 0) {
            // per-wave poll: all 64 producer-wave flags of this team must reach t
            while (__hip_atomic_load(&myflags[lane], __ATOMIC_RELAXED, __HIP_MEMORY_SCOPE_AGENT) <
                   (unsigned)t)
                __builtin_amdgcn_s_sleep(1);
            __builtin_amdgcn_sched_barrier(0);

            // h_{t-1} A-fragments straight from the exchange buffer (row-major [32][512] bf16).
            // 16 device-scope (sc1) 16B loads off one base, all in flight -> one LLC round trip.
            const char* hb = (const char*)hsteam + ((t + 1) & 1) * 32768 +
                             (rg * 16 + l16) * 1024 + q * 16;
            v4u a0, a1, a2, a3, a4, a5, a6, a7, a8, a9, a10, a11, a12, a13, a14, a15;
            asm volatile(
                "global_load_dwordx4 %0, %16, off sc1\n\t"
                "global_load_dwordx4 %1, %16, off offset:64 sc1\n\t"
                "global_load_dwordx4 %2, %16, off offset:128 sc1\n\t"
                "global_load_dwordx4 %3, %16, off offset:192 sc1\n\t"
                "global_load_dwordx4 %4, %16, off offset:256 sc1\n\t"
                "global_load_dwordx4 %5, %16, off offset:320 sc1\n\t"
                "global_load_dwordx4 %6, %16, off offset:384 sc1\n\t"
                "global_load_dwordx4 %7, %16, off offset:448 sc1\n\t"
                "global_load_dwordx4 %8, %16, off offset:512 sc1\n\t"
                "global_load_dwordx4 %9, %16, off offset:576 sc1\n\t"
                "global_load_dwordx4 %10, %16, off offset:640 sc1\n\t"
                "global_load_dwordx4 %11, %16, off offset:704 sc1\n\t"
                "global_load_dwordx4 %12, %16, off offset:768 sc1\n\t"
                "global_load_dwordx4 %13, %16, off offset:832 sc1\n\t"
                "global_load_dwordx4 %14, %16, off offset:896 sc1\n\t"
                "global_load_dwordx4 %15, %16, off offset:960 sc1"
                : "=&v"(a0), "=&v"(a1), "=&v"(a2), "=&v"(a3), "=&v"(a4), "=&v"(a5), "=&v"(a6),
                  "=&v"(a7), "=&v"(a8), "=&v"(a9), "=&v"(a10), "=&v"(a11), "=&v"(a12), "=&v"(a13),
                  "=&v"(a14), "=&v"(a15)
                : "v"(hb)
                : "memory");
            asm volatile("s_waitcnt vmcnt(0)" ::: "memory");
            __builtin_amdgcn_sched_barrier(0);

            v8s af[16];
            af[0] = __builtin_bit_cast(v8s, a0);
            af[1] = __builtin_bit_cast(v8s, a1);
            af[2] = __builtin_bit_cast(v8s, a2);
            af[3] = __builtin_bit_cast(v8s, a3);
            af[4] = __builtin_bit_cast(v8s, a4);
            af[5] = __builtin_bit_cast(v8s, a5);
            af[6] = __builtin_bit_cast(v8s, a6);
            af[7] = __builtin_bit_cast(v8s, a7);
            af[8] = __builtin_bit_cast(v8s, a8);
            af[9] = __builtin_bit_cast(v8s, a9);
            af[10] = __builtin_bit_cast(v8s, a10);
            af[11] = __builtin_bit_cast(v8s, a11);
            af[12] = __builtin_bit_cast(v8s, a12);
            af[13] = __builtin_bit_cast(v8s, a13);
            af[14] = __builtin_bit_cast(v8s, a14);
            af[15] = __builtin_bit_cast(v8s, a15);

#pragma unroll
            for (int kf = 0; kf < 16; kf++)
#pragma unroll
                for (int g = 0; g < 3; g++)
                    acc[g] = __builtin_amdgcn_mfma_f32_16x16x32_bf16(af[kf], bfr[g][kf], acc[g], 0, 0, 0);
        }

        // combine gates, update h, publish exchange slice (sc1 dword stores)
        unsigned int* dst = hsteam + (t & 1) * 8192;
        unsigned short hv[4];
#pragma unroll
        for (int r = 0; r < 4; r++) {
            float rr = sigm(gir[0][r] + bi[0] + acc[0][r] + bh[0]);
            float zz = sigm(gir[1][r] + bi[1] + acc[1][r] + bh[1]);
            float nn = tanh_fast(gir[2][r] + bi[2] + rr * (acc[2][r] + bh[2]));
            float hn = (1.f - zz) * nn + zz * hreg[r];
            hreg[r] = hn;
            hv[r] = f2bf(hn);
            float pv = __shfl_xor(hn, 1);
            if ((l16 & 1) == 0) {
                unsigned int pack = (unsigned int)hv[r] | ((unsigned int)f2bf(pv) << 16);
                int row = rg * 16 + q * 4 + r;
                __hip_atomic_store(&dst[row * 256 + (j >> 1)], pack, __ATOMIC_RELAXED,
                                   __HIP_MEMORY_SCOPE_AGENT);
            }
        }

        // drain this wave's sc1 stores to the coherence point, then publish per-wave flag
        asm volatile("s_waitcnt vmcnt(0)" ::: "memory");
        if (lane == 0)
            __hip_atomic_store(&myflags[cb * 4 + wave], (unsigned)(t + 1), __ATOMIC_RELAXED,
                               __HIP_MEMORY_SCOPE_AGENT);

        // off the critical path: final output + next-step gi prefetch
#pragma unroll
        for (int r = 0; r < 4; r++) {
            int row = rg * 16 + q * 4 + r;
            hout[((long)(bg * 32 + row) * 64 + s) * 1024 + d * 512 + j] = hv[r];
        }
        if (t < 63) {
            int sn = d ? (62 - t) : (t + 1);
            const float* gp =
                gi + (((((long)(d * 64 + sn)) * 8 + bg) * 16 + cb) * 4 + wave) * 768 + lane * 4;
#pragma unroll
            for (int g = 0; g < 3; g++) gir[g] = __builtin_nontemporal_load((const v4f*)(gp + g * 256));
        }
    }
}

extern "C" void kernel_launch(void* const* d_in, const int* in_sizes, int n_in,
                              void* d_out, int out_size, void* d_ws, size_t ws_size,
                              hipStream_t stream) {
    const int* slot_ids = (const int*)d_in[0];
    const float* value_embeds = (const float*)d_in[1];
    const float* embed_table = (const float*)d_in[2];
    const float* W_ih_f = (const float*)d_in[3];
    const float* W_hh_f = (const float*)d_in[4];
    const float* b_ih_f = (const float*)d_in[5];
    const float* b_hh_f = (const float*)d_in[6];
    const float* W_ih_b = (const float*)d_in[7];
    const float* W_hh_b = (const float*)d_in[8];
    const float* b_ih_b = (const float*)d_in[9];
    const float* b_hh_b = (const float*)d_in[10];
    const float* W_proj = (const float*)d_in[11];
    float* out = (float*)d_out;
    char* ws = (char*)d_ws;

    // workspace layout (bytes)
    unsigned short* X = (unsigned short*)(ws + 0);              // 16384x1024 bf16 = 33,554,432
    float* gi = (float*)(ws + 33554432);                        // 50,331,648 f32 = 201,326,592
    unsigned short* Wstk = (unsigned short*)(ws + 234881024);   // 3072x1024 bf16 = 6,291,456 (dead after gemm1)
    unsigned short* Wpk = (unsigned short*)(ws + 241172480);    // 2x96x16x64x8 bf16 = 3,145,728
    unsigned short* Wp = (unsigned short*)(ws + 244318208);     // 512x1024 bf16 = 1,048,576
    unsigned short* hout = X;  // alias: X dead after gemm1
    // h-share + flags alias the (dead-after-gemm1) Wstk region
    unsigned int* hshd = (unsigned int*)Wstk;                   // 16*2*8192 dwords = 1 MB
    unsigned int* flags = (unsigned int*)(ws + 234881024 + 1048576);  // 1024 dwords

    cvt_bf16<<<6144, 256, 0, stream>>>(W_ih_f, Wstk, 1536 * 1024);
    cvt_bf16<<<6144, 256, 0, stream>>>(W_ih_b, Wstk + 1536 * 1024, 1536 * 1024);
    repack_whh<<<3072, 256, 0, stream>>>(W_hh_f, Wpk);
    repack_whh<<<3072, 256, 0, stream>>>(W_hh_b, Wpk + 786432);
    cvt_bf16<<<2048, 256, 0, stream>>>(W_proj, Wp, 512 * 1024);
    build_x<<<16384, 256, 0, stream>>>(slot_ids, value_embeds, embed_table, X);

    // gi = X @ [Wih_f; Wih_b]^T  (M=16384, N=3072, K=1024), packed epilogue
    gemm_bt<1><<<dim3(24, 128), 256, 0, stream>>>(X, Wstk, gi, 16384, 3072, 1024);

    // zero flags (after gemm1: aliases Wstk region)
    init_flags<<<4, 256, 0, stream>>>(flags);

    // recurrence: 256 co-resident blocks, all-register, per-wave flag sync
    gru_rec<<<256, 256, 0, stream>>>(gi, Wpk, b_ih_f, b_hh_f, b_ih_b, b_hh_b, hout, hshd, flags);

    // out = hcat @ W_proj^T   (M=16384, N=512, K=1024)
    gemm_bt<0><<<dim3(4, 128), 256, 0, stream>>>(hout, Wp, out, 16384, 512, 1024);
}